// Round 1
// baseline (229.109 us; speedup 1.0000x reference)
//
#include <hip/hip_runtime.h>
#include <hip/hip_bf16.h>
#include <math.h>
#include <stdint.h>

// InfoNCE fused: sim = A @ B^T / T  (8192x8192x512, fp32 in)
// loss = mean_i( logsumexp_j sim[i,j] - sim[i,i] )
// Plan: bf16 MFMA GEMM fused with online logsumexp (flash-style), diag in fp32.

#define NB 8192
#define DDIM 512
#define SPLITS 8
#define BM 128
#define BN 128
#define BK 32
#define CPB (NB / SPLITS)   // 1024 cols per block
#define TPB (CPB / BN)      // 8 col tiles per block

typedef unsigned short u16;
typedef __attribute__((ext_vector_type(8))) short short8;
typedef __attribute__((ext_vector_type(4))) float f32x4;

__device__ __forceinline__ u16 f2bf(float f) {
  unsigned u = __float_as_uint(f);
  u += 0x7FFFu + ((u >> 16) & 1u);   // round-to-nearest-even
  return (u16)(u >> 16);
}

// global -> LDS direct copy, 16B per lane. LDS dest must be wave-uniform base;
// HW writes base + lane*16. Cast via uintptr: low 32 bits of a generic LDS
// pointer are the LDS offset (CK relies on the same invariant for M0).
__device__ __forceinline__ void gl2lds16(const u16* g, const u16* l) {
  __builtin_amdgcn_global_load_lds(
      (__attribute__((address_space(1))) unsigned int*)(uintptr_t)g,
      (__attribute__((address_space(3))) unsigned int*)(unsigned int)(uintptr_t)l,
      16, 0, 0);
}

__global__ void cvt_kernel(const float* __restrict__ a, const float* __restrict__ p,
                           u16* __restrict__ ab, u16* __restrict__ pb) {
  int i = (blockIdx.x * 256 + threadIdx.x) * 4;
  const float* src = blockIdx.y ? p : a;
  u16* dst = blockIdx.y ? pb : ab;
  float4 v = *(const float4*)(src + i);
  ushort4 o;
  o.x = f2bf(v.x); o.y = f2bf(v.y); o.z = f2bf(v.z); o.w = f2bf(v.w);
  *(ushort4*)(dst + i) = o;
}

__global__ void diag_kernel(const float* __restrict__ a, const float* __restrict__ p,
                            float* __restrict__ diag) {
  int w = (blockIdx.x * blockDim.x + threadIdx.x) >> 6;  // row, one wave per row
  int lane = threadIdx.x & 63;
  const float* ar = a + (size_t)w * DDIM;
  const float* pr = p + (size_t)w * DDIM;
  float s = 0.f;
#pragma unroll
  for (int j = 0; j < DDIM / 64; ++j) s += ar[lane + j * 64] * pr[lane + j * 64];
  for (int off = 32; off > 0; off >>= 1) s += __shfl_down(s, off);
  if (lane == 0) diag[w] = s * 10.0f;  // / T
}

__global__ __launch_bounds__(256, 2) void gemm_lse(
    const u16* __restrict__ Abf, const u16* __restrict__ Bbf,
    float* __restrict__ partM, float* __restrict__ partL) {
  __shared__ u16 sA[BM * BK];   // 8 KB
  __shared__ u16 sB[BN * BK];   // 8 KB
  __shared__ float sPm[2][BM];
  __shared__ float sPs[2][BM];
  __shared__ float sM[BM];
  __shared__ float sL[BM];

  const int tid = threadIdx.x;
  const int wave = tid >> 6;
  const int lane = tid & 63;
  const int quad = lane >> 4;
  const int l16 = lane & 15;
  const int wr = wave >> 1, wc = wave & 1;  // 2x2 wave grid, each 64x64

  const int row0 = blockIdx.y * BM;
  const int col0 = blockIdx.x * CPB;

  if (tid < BM) { sM[tid] = -INFINITY; sL[tid] = 0.f; }

  // staging coords: each wave fills 1KB LDS chunks; lane covers (row, 8 k's)
  const int rsub = lane >> 2;         // 0..15 row within chunk
  const int ksub = (lane & 3) * 8;    // k elem offset
  const u16* aBase = Abf + (size_t)(row0 + wave * 16 + rsub) * DDIM + ksub;
  const u16* ldsA0 = &sA[wave * 512];
  const u16* ldsA1 = &sA[2048 + wave * 512];
  const u16* ldsB0 = &sB[wave * 512];
  const u16* ldsB1 = &sB[2048 + wave * 512];

  // fragment read pointers (A: m=l16, k=quad*8+j ; B: n=l16, same)
  const u16* pa = &sA[(wr * 64 + l16) * BK + quad * 8];
  const u16* pb = &sB[(wc * 64 + l16) * BK + quad * 8];

  for (int t = 0; t < TPB; ++t) {
    const u16* bBase = Bbf + (size_t)(col0 + t * BN + wave * 16 + rsub) * DDIM + ksub;

    f32x4 acc[4][4];
#pragma unroll
    for (int mi = 0; mi < 4; ++mi)
#pragma unroll
      for (int ni = 0; ni < 4; ++ni) acc[mi][ni] = (f32x4){0.f, 0.f, 0.f, 0.f};

    for (int kk = 0; kk < DDIM; kk += BK) {
      __syncthreads();  // protect LDS from previous iteration's readers
      gl2lds16(aBase + kk, ldsA0);
      gl2lds16(aBase + 64 * DDIM + kk, ldsA1);
      gl2lds16(bBase + kk, ldsB0);
      gl2lds16(bBase + 64 * DDIM + kk, ldsB1);
      __syncthreads();  // staging complete (vmcnt drained by barrier)

      short8 af[4], bq[4];
#pragma unroll
      for (int i = 0; i < 4; ++i) {
        af[i] = *(const short8*)(pa + i * 16 * BK);
        bq[i] = *(const short8*)(pb + i * 16 * BK);
      }
#pragma unroll
      for (int mi = 0; mi < 4; ++mi)
#pragma unroll
        for (int ni = 0; ni < 4; ++ni)
          acc[mi][ni] =
              __builtin_amdgcn_mfma_f32_16x16x32_bf16(af[mi], bq[ni], acc[mi][ni], 0, 0, 0);
    }

    // ---- online logsumexp update for this 128x128 tile ----
    // D layout: row = quad*4 + r, col = l16 (within 16x16 fragment)
#pragma unroll
    for (int mi = 0; mi < 4; ++mi) {
#pragma unroll
      for (int r = 0; r < 4; ++r) {
        float v0 = acc[mi][0][r] * 10.0f;  // apply 1/T
        float v1 = acc[mi][1][r] * 10.0f;
        float v2 = acc[mi][2][r] * 10.0f;
        float v3 = acc[mi][3][r] * 10.0f;
        float mx = fmaxf(fmaxf(v0, v1), fmaxf(v2, v3));
        mx = fmaxf(mx, __shfl_xor(mx, 1));
        mx = fmaxf(mx, __shfl_xor(mx, 2));
        mx = fmaxf(mx, __shfl_xor(mx, 4));
        mx = fmaxf(mx, __shfl_xor(mx, 8));
        float s = __expf(v0 - mx) + __expf(v1 - mx) + __expf(v2 - mx) + __expf(v3 - mx);
        s += __shfl_xor(s, 1);
        s += __shfl_xor(s, 2);
        s += __shfl_xor(s, 4);
        s += __shfl_xor(s, 8);
        if (l16 == 0) {
          int rl = wr * 64 + mi * 16 + quad * 4 + r;
          sPm[wc][rl] = mx;
          sPs[wc][rl] = s;
        }
      }
    }
    __syncthreads();
    if (tid < BM) {
      float m0 = sPm[0][tid], m1 = sPm[1][tid];
      float s0 = sPs[0][tid], s1 = sPs[1][tid];
      float tm = fmaxf(m0, m1);
      float ts = s0 * __expf(m0 - tm) + s1 * __expf(m1 - tm);
      float M = sM[tid], L = sL[tid];
      float nm = fmaxf(M, tm);
      sL[tid] = L * __expf(M - nm) + ts * __expf(tm - nm);
      sM[tid] = nm;
    }
    // next iteration's first __syncthreads protects sPm/sM reuse
  }

  if (tid < BM) {
    size_t o = (size_t)blockIdx.x * NB + row0 + tid;
    partM[o] = sM[tid];
    partL[o] = sL[tid];
  }
}

__global__ void finalize_kernel(const float* __restrict__ partM,
                                const float* __restrict__ partL,
                                const float* __restrict__ diag, float* __restrict__ out) {
  __shared__ float red[256];
  float acc = 0.f;
  for (int r = threadIdx.x; r < NB; r += 256) {
    float M = -INFINITY;
#pragma unroll
    for (int s = 0; s < SPLITS; ++s) M = fmaxf(M, partM[(size_t)s * NB + r]);
    float L = 0.f;
#pragma unroll
    for (int s = 0; s < SPLITS; ++s)
      L += partL[(size_t)s * NB + r] * __expf(partM[(size_t)s * NB + r] - M);
    acc += M + __logf(L) - diag[r];
  }
  red[threadIdx.x] = acc;
  __syncthreads();
  for (int s = 128; s > 0; s >>= 1) {
    if (threadIdx.x < s) red[threadIdx.x] += red[threadIdx.x + s];
    __syncthreads();
  }
  if (threadIdx.x == 0) out[0] = red[0] * (1.0f / (float)NB);
}

extern "C" void kernel_launch(void* const* d_in, const int* in_sizes, int n_in,
                              void* d_out, int out_size, void* d_ws, size_t ws_size,
                              hipStream_t stream) {
  const float* anchor = (const float*)d_in[0];
  const float* positive = (const float*)d_in[1];
  float* out = (float*)d_out;

  char* ws = (char*)d_ws;
  u16* Abf = (u16*)ws;                                   // 8 MB
  u16* Bbf = (u16*)(ws + (size_t)8388608);               // 8 MB
  float* diag = (float*)(ws + (size_t)16777216);         // 32 KB
  float* partM = (float*)(ws + (size_t)16777216 + 32768);
  float* partL = (float*)(ws + (size_t)16777216 + 32768 + (size_t)SPLITS * NB * 4);

  cvt_kernel<<<dim3(NB * DDIM / 4 / 256, 2), 256, 0, stream>>>(anchor, positive, Abf, Bbf);
  diag_kernel<<<NB / 4, 256, 0, stream>>>(anchor, positive, diag);
  gemm_lse<<<dim3(SPLITS, NB / BM), 256, 0, stream>>>(Abf, Bbf, partM, partL);
  finalize_kernel<<<1, 256, 0, stream>>>(partM, partL, diag, out);
}